// Round 5
// baseline (303.307 us; speedup 1.0000x reference)
//
#include <hip/hip_runtime.h>
#include <stdint.h>

#define B_ 4
#define N_ 16384
#define M_ 4096
#define C_ 64
#define S_ 32
#define R2_ 0.16f   // float(0.4*0.4)
#define GDIM 32
#define CELLS 32768       // 32^3 cells per batch, edge 0.5 over [-8, 8)
#define CSTRIDE 32772     // padded per-batch stride (>= CELLS+1)

// ---- workspace layout (high-water 19.9 MB, proven safe) ----
// xyz4: [B][N] float4 {x,y,z,pp}      @ 0        (1 MB)
// ft:   [B][N][C] float (transposed)  @ 1 MB     (16 MB)  -- written AFTER ball query
//   grid arrays overlay the ft region (dead once ball_query completes):
//   start: [B][CSTRIDE] int           @ 1 MB
//   cur:   [B][CSTRIDE] int           @ +524352
//   spts:  [B][N] float4 (cell-sorted)@ +524352
//   ssid:  [B][N] int (orig index)    @ +1 MB
// idx:  [B][M][S] int                 @ 17 MB    (2 MB)
static const size_t OFF_XYZ4  = 0;
static const size_t OFF_FT    = (size_t)B_ * N_ * 4 * sizeof(float);          // 1,048,576
static const size_t OFF_IDX   = OFF_FT + (size_t)B_ * N_ * C_ * sizeof(float);
static const size_t OFF_START = OFF_FT;                                        // overlay
static const size_t OFF_CUR   = OFF_START + (size_t)B_ * CSTRIDE * sizeof(int);
static const size_t OFF_SPTS  = OFF_CUR + (size_t)B_ * CSTRIDE * sizeof(int);
static const size_t OFF_SSID  = OFF_SPTS + (size_t)B_ * N_ * 4 * sizeof(float);

__device__ __forceinline__ int cellof(float v) {
    int c = (int)floorf((v + 8.0f) * 2.0f);   // edge 0.5; coverage margin 0.5 > r
    return c < 0 ? 0 : (c > GDIM - 1 ? GDIM - 1 : c);
}

// A1: pack xyz into float4 {x,y,z,pp}, pp per-op rounded (bit-exact vs ref); zero cell counters
__global__ __launch_bounds__(256) void pack_xyz4(const float* __restrict__ xyz,
                                                 float4* __restrict__ xyz4,
                                                 int* __restrict__ cur) {
    int i = blockIdx.x * 256 + threadIdx.x;       // [0, B*N)
    for (int j = i; j < B_ * CSTRIDE; j += B_ * N_) cur[j] = 0;
    float x = xyz[3 * i + 0];
    float y = xyz[3 * i + 1];
    float z = xyz[3 * i + 2];
    float pp = __fadd_rn(__fadd_rn(__fmul_rn(x, x), __fmul_rn(y, y)), __fmul_rn(z, z));
    xyz4[i] = make_float4(x, y, z, pp);
}

// G1: per-cell histogram
__global__ __launch_bounds__(256) void hist_cells(const float* __restrict__ xyz,
                                                  int* __restrict__ cur) {
    int i = blockIdx.x * 256 + threadIdx.x;       // [0, B*N)
    int b = i >> 14;
    float x = xyz[3 * i + 0];
    float y = xyz[3 * i + 1];
    float z = xyz[3 * i + 2];
    int cid = (cellof(z) << 10) | (cellof(y) << 5) | cellof(x);
    atomicAdd(&cur[b * CSTRIDE + cid], 1);
}

// G2: exclusive scan of 32768 cell counts per batch (one block per batch);
// writes start[] (+ sentinel start[CELLS]=N) and resets cur[] to start (scatter cursor)
__global__ __launch_bounds__(1024) void scan_cells(int* __restrict__ cur,
                                                   int* __restrict__ start) {
    __shared__ int ls[1024];
    int b = blockIdx.x, t = threadIdx.x;
    int* cb = cur + b * CSTRIDE;
    int* sb = start + b * CSTRIDE;
    int base = t * 32;                 // 1024 threads x 32 cells = 32768
    int loc[32]; int tot = 0;
    #pragma unroll
    for (int j = 0; j < 32; ++j) { loc[j] = cb[base + j]; tot += loc[j]; }
    ls[t] = tot; __syncthreads();
    for (int d = 1; d < 1024; d <<= 1) {
        int v = (t >= d) ? ls[t - d] : 0; __syncthreads();
        ls[t] += v; __syncthreads();
    }
    int run = ls[t] - tot;             // exclusive prefix of this thread's span
    #pragma unroll
    for (int j = 0; j < 32; ++j) { sb[base + j] = run; cb[base + j] = run; run += loc[j]; }
    if (t == 0) sb[CELLS] = N_;
}

// G3: scatter points into cell-sorted order (intra-cell order irrelevant; selection sorts by index)
__global__ __launch_bounds__(256) void scatter_pts(const float4* __restrict__ xyz4,
                                                   int* __restrict__ cur,
                                                   float4* __restrict__ spts,
                                                   int* __restrict__ ssid) {
    int i = blockIdx.x * 256 + threadIdx.x;       // [0, B*N)
    int b = i >> 14, n = i & (N_ - 1);
    float4 P = xyz4[i];
    int cid = (cellof(P.z) << 10) | (cellof(P.y) << 5) | cellof(P.x);
    int pos = atomicAdd(&cur[b * CSTRIDE + cid], 1);
    spts[(size_t)b * N_ + pos] = P;
    ssid[b * N_ + pos] = n;
}

// B: grid ball query — one wave per query. Gather in-ball hits from the 27
// neighbor cells into an LDS list, then extract the 32 smallest original
// indices (== reference's first-32-by-index, ascending). Distance chain bit-exact.
__global__ __launch_bounds__(256) void ball_query_grid(const float4* __restrict__ spts,
                                                       const int* __restrict__ ssid,
                                                       const int* __restrict__ start,
                                                       const float* __restrict__ newxyz,
                                                       int* __restrict__ idx) {
    __shared__ int hitsAll[4 * 1024];
    int tid = threadIdx.x, lane = tid & 63, w = tid >> 6;
    int* hits = hitsAll + w * 1024;
    int gw = blockIdx.x * 4 + w;                  // 0..16383
    int b = gw >> 12;
    int m = gw & (M_ - 1);
    size_t qb = ((size_t)b * M_ + m) * 3;
    float qx = newxyz[qb + 0], qy = newxyz[qb + 1], qz = newxyz[qb + 2];
    float qq = __fadd_rn(__fadd_rn(__fmul_rn(qx, qx), __fmul_rn(qy, qy)), __fmul_rn(qz, qz));
    int cx = cellof(qx), cy = cellof(qy), cz = cellof(qz);
    const float4* sp  = spts + (size_t)b * N_;
    const int*    sid = ssid + b * N_;
    const int*    st  = start + b * CSTRIDE;
    unsigned long long lmlt = (1ull << lane) - 1ull;
    int cnt = 0;

    for (int dz = -1; dz <= 1; ++dz) { int nz = cz + dz; if ((unsigned)nz >= GDIM) continue;
    for (int dy = -1; dy <= 1; ++dy) { int ny = cy + dy; if ((unsigned)ny >= GDIM) continue;
    for (int dx = -1; dx <= 1; ++dx) { int nx = cx + dx; if ((unsigned)nx >= GDIM) continue;
        int cid = (nz << 10) | (ny << 5) | nx;
        int s = st[cid], e = st[cid + 1];
        for (int off = s; off < e; off += 64) {
            int i = off + lane;
            bool inb = false; int oidx = 0;
            if (i < e) {
                float4 P = sp[i];
                float dot = __fmaf_rn(qz, P.z, __fmaf_rn(qy, P.y, __fmul_rn(qx, P.x)));
                float d2  = __fsub_rn(__fadd_rn(qq, P.w), __fmul_rn(2.0f, dot));
                if (d2 < R2_) { inb = true; oidx = sid[i]; }
            }
            unsigned long long mk = __ballot(inb);
            if (mk) {
                int rank = __popcll(mk & lmlt);
                int pos  = cnt + rank;
                if (inb && pos < 1024) hits[pos] = oidx;
                cnt += __popcll(mk);
            }
        }
    }}}
    __builtin_amdgcn_wave_barrier();
    if (cnt > 1024) cnt = 1024;        // statistically unreachable (max count ~350)
    int kk = cnt < S_ ? cnt : S_;
    int sel = 0, firstv = 0;
    for (int k = 0; k < kk; ++k) {
        int v = 0x7fffffff;
        for (int j = lane; j < cnt; j += 64) v = min(v, hits[j]);
        #pragma unroll
        for (int o = 32; o; o >>= 1) { int u = __shfl_xor(v, o); v = min(v, u); }
        for (int j = lane; j < cnt; j += 64) if (hits[j] == v) hits[j] = 0x7fffffff;
        __builtin_amdgcn_wave_barrier();
        if (k == 0) firstv = v;
        if (lane == k) sel = v;
    }
    if (lane >= kk) sel = firstv;      // pad with smallest in-ball index (0 if none)
    if (lane < S_) idx[((size_t)b * M_ + m) * S_ + lane] = sel;
}

// A2: transpose features (B,C,N) -> (B,N,C)  [runs AFTER ball query: overwrites grid arrays]
__global__ __launch_bounds__(256) void transpose_feat(const float* __restrict__ f,
                                                      float* __restrict__ ft) {
    __shared__ float tile[64][65];
    int b  = blockIdx.x >> 8;
    int n0 = (blockIdx.x & 255) << 6;
    int tid  = threadIdx.x;
    int lane = tid & 63;
    int grp  = tid >> 6;
    #pragma unroll
    for (int r = 0; r < 16; ++r) {
        int c = r * 4 + grp;
        tile[c][lane] = f[((size_t)b * C_ + c) * N_ + n0 + lane];
    }
    __syncthreads();
    #pragma unroll
    for (int r = 0; r < 16; ++r) {
        int nl = r * 4 + grp;
        ft[((size_t)b * N_ + n0 + nl) * C_ + lane] = tile[lane][nl];
    }
}

// C: gather + assemble output (B, 67, M, S). One block per (b,m).
__global__ __launch_bounds__(256) void group_out(const float4* __restrict__ xyz4,
                                                 const float* __restrict__ ft,
                                                 const float* __restrict__ newxyz,
                                                 const int* __restrict__ idx,
                                                 float* __restrict__ out) {
    __shared__ int   sidx[32];
    __shared__ float q[3];
    int tid = threadIdx.x;
    int b   = blockIdx.x >> 12;
    int m   = blockIdx.x & 4095;
    if (tid < 32) sidx[tid] = idx[((size_t)b * M_ + m) * S_ + tid];
    if (tid < 3)  q[tid]    = newxyz[((size_t)b * M_ + m) * 3 + tid];
    __syncthreads();

    int s  = tid & 31;
    int c8 = tid >> 5;
    int p  = sidx[s];

    const float* fp = ft + ((size_t)b * N_ + p) * C_ + c8 * 8;
    float4 v0 = *(const float4*)(fp);
    float4 v1 = *(const float4*)(fp + 4);

    const size_t st = (size_t)M_ * S_;
    size_t ob = (((size_t)b * 67 + 3 + c8 * 8) * M_ + m) * S_ + s;
    out[ob + 0 * st] = v0.x;
    out[ob + 1 * st] = v0.y;
    out[ob + 2 * st] = v0.z;
    out[ob + 3 * st] = v0.w;
    out[ob + 4 * st] = v1.x;
    out[ob + 5 * st] = v1.y;
    out[ob + 6 * st] = v1.z;
    out[ob + 7 * st] = v1.w;

    if (tid < 32) {
        float4 P = xyz4[(size_t)b * N_ + p];
        size_t xb = (((size_t)b * 67 + 0) * M_ + m) * S_ + s;
        out[xb + 0 * st] = P.x - q[0];
        out[xb + 1 * st] = P.y - q[1];
        out[xb + 2 * st] = P.z - q[2];
    }
}

extern "C" void kernel_launch(void* const* d_in, const int* in_sizes, int n_in,
                              void* d_out, int out_size, void* d_ws, size_t ws_size,
                              hipStream_t stream) {
    const float* xyz    = (const float*)d_in[0];   // (B, N, 3)
    const float* newxyz = (const float*)d_in[1];   // (B, M, 3)
    const float* feat   = (const float*)d_in[2];   // (B, C, N)
    float* out = (float*)d_out;                    // (B, 67, M, S)

    char* ws = (char*)d_ws;
    float4* xyz4  = (float4*)(ws + OFF_XYZ4);
    float*  ft    = (float*)(ws + OFF_FT);
    int*    idxb  = (int*)(ws + OFF_IDX);
    int*    startc= (int*)(ws + OFF_START);
    int*    curc  = (int*)(ws + OFF_CUR);
    float4* spts  = (float4*)(ws + OFF_SPTS);
    int*    ssid  = (int*)(ws + OFF_SSID);

    pack_xyz4     <<<(B_ * N_) / 256, 256, 0, stream>>>(xyz, xyz4, curc);
    hist_cells    <<<(B_ * N_) / 256, 256, 0, stream>>>(xyz, curc);
    scan_cells    <<<B_, 1024, 0, stream>>>(curc, startc);
    scatter_pts   <<<(B_ * N_) / 256, 256, 0, stream>>>(xyz4, curc, spts, ssid);
    ball_query_grid<<<(B_ * M_) / 4, 256, 0, stream>>>(spts, ssid, startc, newxyz, idxb);
    transpose_feat<<<B_ * (N_ / 64), 256, 0, stream>>>(feat, ft);
    group_out     <<<B_ * M_, 256, 0, stream>>>(xyz4, ft, newxyz, idxb, out);
}

// Round 6
// 234.078 us; speedup vs baseline: 1.2958x; 1.2958x over previous
//
#include <hip/hip_runtime.h>
#include <stdint.h>

#define B_ 4
#define N_ 16384
#define M_ 4096
#define C_ 64
#define S_ 32
#define R2_ 0.16f   // float(0.4*0.4)
#define GDIM 32
#define CELLS 32768       // 32^3 cells per batch, edge 0.5 over [-8, 8)
#define CSTRIDE 32772     // padded per-batch stride (>= CELLS+1)

// ---- workspace layout (high-water 19.9 MB, proven safe) ----
// xyz4: [B][N] float4 {x,y,z,pp}      @ 0        (1 MB)
// ft:   [B][N][C] float (transposed)  @ 1 MB     (16 MB)  -- written AFTER ball query
//   grid arrays overlay the ft region (dead once ball_query completes):
//   start: [B][CSTRIDE] int           @ 1 MB
//   cur:   [B][CSTRIDE] int           @ +524352
//   spts:  [B][N] float4 (cell-sorted)@ +524352
//   ssid:  [B][N] int (orig index)    @ +1 MB
// idx:  [B][M][S] int                 @ 17 MB    (2 MB)
static const size_t OFF_XYZ4  = 0;
static const size_t OFF_FT    = (size_t)B_ * N_ * 4 * sizeof(float);          // 1,048,576
static const size_t OFF_IDX   = OFF_FT + (size_t)B_ * N_ * C_ * sizeof(float);
static const size_t OFF_START = OFF_FT;                                        // overlay
static const size_t OFF_CUR   = OFF_START + (size_t)B_ * CSTRIDE * sizeof(int);
static const size_t OFF_SPTS  = OFF_CUR + (size_t)B_ * CSTRIDE * sizeof(int);
static const size_t OFF_SSID  = OFF_SPTS + (size_t)B_ * N_ * 4 * sizeof(float);

__device__ __forceinline__ int cellof(float v) {
    int c = (int)floorf((v + 8.0f) * 2.0f);   // edge 0.5; coverage margin 0.5 > r
    return c < 0 ? 0 : (c > GDIM - 1 ? GDIM - 1 : c);
}

// A1: pack xyz into float4 {x,y,z,pp}, pp per-op rounded (bit-exact vs ref); zero cell counters
__global__ __launch_bounds__(256) void pack_xyz4(const float* __restrict__ xyz,
                                                 float4* __restrict__ xyz4,
                                                 int* __restrict__ cur) {
    int i = blockIdx.x * 256 + threadIdx.x;       // [0, B*N)
    for (int j = i; j < B_ * CSTRIDE; j += B_ * N_) cur[j] = 0;
    float x = xyz[3 * i + 0];
    float y = xyz[3 * i + 1];
    float z = xyz[3 * i + 2];
    float pp = __fadd_rn(__fadd_rn(__fmul_rn(x, x), __fmul_rn(y, y)), __fmul_rn(z, z));
    xyz4[i] = make_float4(x, y, z, pp);
}

// G1: per-cell histogram
__global__ __launch_bounds__(256) void hist_cells(const float* __restrict__ xyz,
                                                  int* __restrict__ cur) {
    int i = blockIdx.x * 256 + threadIdx.x;       // [0, B*N)
    int b = i >> 14;
    float x = xyz[3 * i + 0];
    float y = xyz[3 * i + 1];
    float z = xyz[3 * i + 2];
    int cid = (cellof(z) << 10) | (cellof(y) << 5) | cellof(x);
    atomicAdd(&cur[b * CSTRIDE + cid], 1);
}

// G2: exclusive scan of 32768 cell counts per batch (one block per batch);
// writes start[] (+ sentinel start[CELLS]=N) and resets cur[] to start (scatter cursor)
__global__ __launch_bounds__(1024) void scan_cells(int* __restrict__ cur,
                                                   int* __restrict__ start) {
    __shared__ int ls[1024];
    int b = blockIdx.x, t = threadIdx.x;
    int* cb = cur + b * CSTRIDE;
    int* sb = start + b * CSTRIDE;
    int base = t * 32;                 // 1024 threads x 32 cells = 32768
    int loc[32]; int tot = 0;
    #pragma unroll
    for (int j = 0; j < 32; ++j) { loc[j] = cb[base + j]; tot += loc[j]; }
    ls[t] = tot; __syncthreads();
    for (int d = 1; d < 1024; d <<= 1) {
        int v = (t >= d) ? ls[t - d] : 0; __syncthreads();
        ls[t] += v; __syncthreads();
    }
    int run = ls[t] - tot;             // exclusive prefix of this thread's span
    #pragma unroll
    for (int j = 0; j < 32; ++j) { sb[base + j] = run; cb[base + j] = run; run += loc[j]; }
    if (t == 0) sb[CELLS] = N_;
}

// G3: scatter points into cell-sorted order (intra-cell order irrelevant; selection sorts by index)
__global__ __launch_bounds__(256) void scatter_pts(const float4* __restrict__ xyz4,
                                                   int* __restrict__ cur,
                                                   float4* __restrict__ spts,
                                                   int* __restrict__ ssid) {
    int i = blockIdx.x * 256 + threadIdx.x;       // [0, B*N)
    int b = i >> 14, n = i & (N_ - 1);
    float4 P = xyz4[i];
    int cid = (cellof(P.z) << 10) | (cellof(P.y) << 5) | cellof(P.x);
    int pos = atomicAdd(&cur[b * CSTRIDE + cid], 1);
    spts[(size_t)b * N_ + pos] = P;
    ssid[b * N_ + pos] = n;
}

// B: grid ball query — one wave per query. In-ball hits are recorded as bits in
// a 16384-bit LDS bitmap (index-ordered by construction); selection is a single
// popcount-prefix pass that emits the 32 smallest original indices ascending,
// padded with the rank-0 index (0 if none). Distance chain bit-exact vs ref.
// The 3 x-contiguous cells per (dz,dy) share one segment: 9 segments total.
__global__ __launch_bounds__(256) void ball_query_grid(const float4* __restrict__ spts,
                                                       const int* __restrict__ ssid,
                                                       const int* __restrict__ start,
                                                       const float* __restrict__ newxyz,
                                                       int* __restrict__ idx) {
    __shared__ unsigned int bmAll[4][512];   // 2 KB bitmap per wave
    __shared__ int bcAll[4];                 // rank-0 broadcast per wave
    int tid = threadIdx.x, lane = tid & 63, w = tid >> 6;
    unsigned int* bm = bmAll[w];
    int gw = blockIdx.x * 4 + w;                  // 0..16383
    int b = gw >> 12;
    int m = gw & (M_ - 1);

    // zero bitmap: each lane clears 32 B
    *(uint4*)&bm[lane * 8]     = make_uint4(0u, 0u, 0u, 0u);
    *(uint4*)&bm[lane * 8 + 4] = make_uint4(0u, 0u, 0u, 0u);
    if (lane == 0) bcAll[w] = 0;

    size_t qb = ((size_t)b * M_ + m) * 3;
    float qx = newxyz[qb + 0], qy = newxyz[qb + 1], qz = newxyz[qb + 2];
    float qq = __fadd_rn(__fadd_rn(__fmul_rn(qx, qx), __fmul_rn(qy, qy)), __fmul_rn(qz, qz));
    int cx = cellof(qx), cy = cellof(qy), cz = cellof(qz);
    const float4* sp  = spts + (size_t)b * N_;
    const int*    sid = ssid + b * N_;
    const int*    st  = start + b * CSTRIDE;
    int x0 = cx > 0 ? cx - 1 : 0;
    int x1 = cx < GDIM - 1 ? cx + 1 : GDIM - 1;
    __builtin_amdgcn_wave_barrier();

    for (int dz = -1; dz <= 1; ++dz) { int nz = cz + dz; if ((unsigned)nz >= GDIM) continue;
    for (int dy = -1; dy <= 1; ++dy) { int ny = cy + dy; if ((unsigned)ny >= GDIM) continue;
        int rowb = (nz << 10) | (ny << 5);
        int s = st[rowb | x0];
        int e = st[(rowb | x1) + 1];
        for (int off = s; off < e; off += 64) {
            int i = off + lane;
            if (i < e) {
                float4 P = sp[i];
                float dot = __fmaf_rn(qz, P.z, __fmaf_rn(qy, P.y, __fmul_rn(qx, P.x)));
                float d2  = __fsub_rn(__fadd_rn(qq, P.w), __fmul_rn(2.0f, dot));
                if (d2 < R2_) {
                    int o = sid[i];
                    atomicOr(&bm[o >> 5], 1u << (o & 31));
                }
            }
        }
    }}
    __builtin_amdgcn_wave_barrier();

    // selection: lane owns dwords 8*lane .. 8*lane+7 (index-contiguous)
    uint4 a = *(const uint4*)&bm[lane * 8];
    uint4 c = *(const uint4*)&bm[lane * 8 + 4];
    unsigned int wds[8] = {a.x, a.y, a.z, a.w, c.x, c.y, c.z, c.w};
    int tl = 0;
    #pragma unroll
    for (int j = 0; j < 8; ++j) tl += __popc(wds[j]);
    int pre = tl;
    #pragma unroll
    for (int o = 1; o < 64; o <<= 1) { int u = __shfl_up(pre, o); if (lane >= o) pre += u; }
    int cnt = __shfl(pre, 63);
    int r = pre - tl;                       // global rank of this lane's first set bit
    int* outp = idx + ((size_t)b * M_ + m) * S_;
    int basei = lane << 8;                  // lane*8 dwords * 32 bits
    #pragma unroll
    for (int wd = 0; wd < 8; ++wd) {
        if (r >= S_) break;
        unsigned int bits = wds[wd];
        while (bits && r < S_) {
            int bpos = __builtin_ctz(bits);
            bits &= bits - 1;
            int gidx = basei + (wd << 5) + bpos;
            if (r == 0) bcAll[w] = gidx;
            outp[r] = gidx;
            ++r;
        }
    }
    __builtin_amdgcn_wave_barrier();
    int firstv = bcAll[w];
    if (lane < S_ && lane >= cnt) outp[lane] = firstv;
}

// A2: transpose features (B,C,N) -> (B,N,C)  [runs AFTER ball query: overwrites grid arrays]
__global__ __launch_bounds__(256) void transpose_feat(const float* __restrict__ f,
                                                      float* __restrict__ ft) {
    __shared__ float tile[64][65];
    int b  = blockIdx.x >> 8;
    int n0 = (blockIdx.x & 255) << 6;
    int tid  = threadIdx.x;
    int lane = tid & 63;
    int grp  = tid >> 6;
    #pragma unroll
    for (int r = 0; r < 16; ++r) {
        int c = r * 4 + grp;
        tile[c][lane] = f[((size_t)b * C_ + c) * N_ + n0 + lane];
    }
    __syncthreads();
    #pragma unroll
    for (int r = 0; r < 16; ++r) {
        int nl = r * 4 + grp;
        ft[((size_t)b * N_ + n0 + nl) * C_ + lane] = tile[lane][nl];
    }
}

// C: gather + assemble output (B, 67, M, S). One block per (b,m).
__global__ __launch_bounds__(256) void group_out(const float4* __restrict__ xyz4,
                                                 const float* __restrict__ ft,
                                                 const float* __restrict__ newxyz,
                                                 const int* __restrict__ idx,
                                                 float* __restrict__ out) {
    __shared__ int   sidx[32];
    __shared__ float q[3];
    int tid = threadIdx.x;
    int b   = blockIdx.x >> 12;
    int m   = blockIdx.x & 4095;
    if (tid < 32) sidx[tid] = idx[((size_t)b * M_ + m) * S_ + tid];
    if (tid < 3)  q[tid]    = newxyz[((size_t)b * M_ + m) * 3 + tid];
    __syncthreads();

    int s  = tid & 31;
    int c8 = tid >> 5;
    int p  = sidx[s];

    const float* fp = ft + ((size_t)b * N_ + p) * C_ + c8 * 8;
    float4 v0 = *(const float4*)(fp);
    float4 v1 = *(const float4*)(fp + 4);

    const size_t st = (size_t)M_ * S_;
    size_t ob = (((size_t)b * 67 + 3 + c8 * 8) * M_ + m) * S_ + s;
    out[ob + 0 * st] = v0.x;
    out[ob + 1 * st] = v0.y;
    out[ob + 2 * st] = v0.z;
    out[ob + 3 * st] = v0.w;
    out[ob + 4 * st] = v1.x;
    out[ob + 5 * st] = v1.y;
    out[ob + 6 * st] = v1.z;
    out[ob + 7 * st] = v1.w;

    if (tid < 32) {
        float4 P = xyz4[(size_t)b * N_ + p];
        size_t xb = (((size_t)b * 67 + 0) * M_ + m) * S_ + s;
        out[xb + 0 * st] = P.x - q[0];
        out[xb + 1 * st] = P.y - q[1];
        out[xb + 2 * st] = P.z - q[2];
    }
}

extern "C" void kernel_launch(void* const* d_in, const int* in_sizes, int n_in,
                              void* d_out, int out_size, void* d_ws, size_t ws_size,
                              hipStream_t stream) {
    const float* xyz    = (const float*)d_in[0];   // (B, N, 3)
    const float* newxyz = (const float*)d_in[1];   // (B, M, 3)
    const float* feat   = (const float*)d_in[2];   // (B, C, N)
    float* out = (float*)d_out;                    // (B, 67, M, S)

    char* ws = (char*)d_ws;
    float4* xyz4  = (float4*)(ws + OFF_XYZ4);
    float*  ft    = (float*)(ws + OFF_FT);
    int*    idxb  = (int*)(ws + OFF_IDX);
    int*    startc= (int*)(ws + OFF_START);
    int*    curc  = (int*)(ws + OFF_CUR);
    float4* spts  = (float4*)(ws + OFF_SPTS);
    int*    ssid  = (int*)(ws + OFF_SSID);

    pack_xyz4     <<<(B_ * N_) / 256, 256, 0, stream>>>(xyz, xyz4, curc);
    hist_cells    <<<(B_ * N_) / 256, 256, 0, stream>>>(xyz, curc);
    scan_cells    <<<B_, 1024, 0, stream>>>(curc, startc);
    scatter_pts   <<<(B_ * N_) / 256, 256, 0, stream>>>(xyz4, curc, spts, ssid);
    ball_query_grid<<<(B_ * M_) / 4, 256, 0, stream>>>(spts, ssid, startc, newxyz, idxb);
    transpose_feat<<<B_ * (N_ / 64), 256, 0, stream>>>(feat, ft);
    group_out     <<<B_ * M_, 256, 0, stream>>>(xyz4, ft, newxyz, idxb, out);
}

// Round 7
// 229.350 us; speedup vs baseline: 1.3225x; 1.0206x over previous
//
#include <hip/hip_runtime.h>
#include <stdint.h>

#define B_ 4
#define N_ 16384
#define M_ 4096
#define C_ 64
#define S_ 32
#define R2_ 0.16f   // float(0.4*0.4)
#define GDIM 32
#define CELLS 32768       // 32^3 cells per batch, edge 0.5 over [-8, 8)
#define CSTRIDE 32772     // padded per-batch stride (>= CELLS+1)

// ---- workspace layout (high-water 19.9 MB, proven safe) ----
// xyz4: [B][N] float4 {x,y,z,pp}      @ 0        (1 MB)
// ft:   [B][N][C] float (transposed)  @ 1 MB     (16 MB)  -- written AFTER ball query
//   grid arrays overlay the ft region (dead once ball_query completes):
//   start: [B][CSTRIDE] int           @ 1 MB
//   cur:   [B][CSTRIDE] int           @ +524352
//   spts:  [B][N] float4 (cell-sorted)@ +524352
//   ssid:  [B][N] int (orig index)    @ +1 MB
// idx:  [B][M][S] int                 @ 17 MB    (2 MB)
static const size_t OFF_XYZ4  = 0;
static const size_t OFF_FT    = (size_t)B_ * N_ * 4 * sizeof(float);          // 1,048,576
static const size_t OFF_IDX   = OFF_FT + (size_t)B_ * N_ * C_ * sizeof(float);
static const size_t OFF_START = OFF_FT;                                        // overlay
static const size_t OFF_CUR   = OFF_START + (size_t)B_ * CSTRIDE * sizeof(int);
static const size_t OFF_SPTS  = OFF_CUR + (size_t)B_ * CSTRIDE * sizeof(int);
static const size_t OFF_SSID  = OFF_SPTS + (size_t)B_ * N_ * 4 * sizeof(float);

__device__ __forceinline__ int cellof(float v) {
    int c = (int)floorf((v + 8.0f) * 2.0f);   // edge 0.5; coverage margin 0.5 > r
    return c < 0 ? 0 : (c > GDIM - 1 ? GDIM - 1 : c);
}

// A1+G1 fused: pack xyz into float4 {x,y,z,pp} (pp per-op rounded, bit-exact vs ref)
// and histogram cells. cur[] zeroed by hipMemsetAsync beforehand.
__global__ __launch_bounds__(256) void pack_hist(const float* __restrict__ xyz,
                                                 float4* __restrict__ xyz4,
                                                 int* __restrict__ cur) {
    int i = blockIdx.x * 256 + threadIdx.x;       // [0, B*N)
    int b = i >> 14;
    float x = xyz[3 * i + 0];
    float y = xyz[3 * i + 1];
    float z = xyz[3 * i + 2];
    float pp = __fadd_rn(__fadd_rn(__fmul_rn(x, x), __fmul_rn(y, y)), __fmul_rn(z, z));
    xyz4[i] = make_float4(x, y, z, pp);
    int cid = (cellof(z) << 10) | (cellof(y) << 5) | cellof(x);
    atomicAdd(&cur[b * CSTRIDE + cid], 1);
}

// G2: exclusive scan of 32768 cell counts per batch (one block per batch).
// v2: wave-shuffle prefix + single cross-wave pass -> 2 barriers (was 20).
// Writes start[] (+ sentinel start[CELLS]=N) and resets cur[] to start.
__global__ __launch_bounds__(1024) void scan_cells(int* __restrict__ cur,
                                                   int* __restrict__ start) {
    __shared__ int ls[16];                 // per-wave totals
    int b = blockIdx.x, t = threadIdx.x;
    int lane = t & 63, w = t >> 6;         // 16 waves
    int* cb = cur + b * CSTRIDE;
    int* sb = start + b * CSTRIDE;
    int base = t * 32;                     // 1024 threads x 32 cells = 32768
    int loc[32]; int tot = 0;
    #pragma unroll
    for (int j = 0; j < 32; ++j) { loc[j] = cb[base + j]; tot += loc[j]; }
    // wave-level inclusive prefix of per-thread totals
    int pre = tot;
    #pragma unroll
    for (int o = 1; o < 64; o <<= 1) { int u = __shfl_up(pre, o); if (lane >= o) pre += u; }
    if (lane == 63) ls[w] = pre;           // wave total
    __syncthreads();
    if (t < 16) {
        int v = ls[t];
        int p16 = v;
        #pragma unroll
        for (int o = 1; o < 16; o <<= 1) { int u = __shfl_up(p16, o); if (t >= o) p16 += u; }
        ls[t] = p16 - v;                   // exclusive wave offset
    }
    __syncthreads();
    int run = ls[w] + (pre - tot);         // exclusive prefix for this thread's span
    #pragma unroll
    for (int j = 0; j < 32; ++j) { sb[base + j] = run; cb[base + j] = run; run += loc[j]; }
    if (t == 0) sb[CELLS] = N_;
}

// G3: scatter points into cell-sorted order (intra-cell order irrelevant; selection sorts by index)
__global__ __launch_bounds__(256) void scatter_pts(const float4* __restrict__ xyz4,
                                                   int* __restrict__ cur,
                                                   float4* __restrict__ spts,
                                                   int* __restrict__ ssid) {
    int i = blockIdx.x * 256 + threadIdx.x;       // [0, B*N)
    int b = i >> 14, n = i & (N_ - 1);
    float4 P = xyz4[i];
    int cid = (cellof(P.z) << 10) | (cellof(P.y) << 5) | cellof(P.x);
    int pos = atomicAdd(&cur[b * CSTRIDE + cid], 1);
    spts[(size_t)b * N_ + pos] = P;
    ssid[b * N_ + pos] = n;
}

// B: grid ball query — one wave per query. In-ball hits are recorded as bits in
// a 16384-bit LDS bitmap (index-ordered by construction); selection is a single
// popcount-prefix pass that emits the 32 smallest original indices ascending,
// padded with the rank-0 index (0 if none). Distance chain bit-exact vs ref.
// The 9 (dz,dy) row-segments (3 x-contiguous cells each) are range-prefetched
// by lanes 0..8 and broadcast via shfl -> scalar loop bounds.
__global__ __launch_bounds__(256) void ball_query_grid(const float4* __restrict__ spts,
                                                       const int* __restrict__ ssid,
                                                       const int* __restrict__ start,
                                                       const float* __restrict__ newxyz,
                                                       int* __restrict__ idx) {
    __shared__ unsigned int bmAll[4][512];   // 2 KB bitmap per wave
    __shared__ int bcAll[4];                 // rank-0 broadcast per wave
    int tid = threadIdx.x, lane = tid & 63, w = tid >> 6;
    unsigned int* bm = bmAll[w];
    int gw = blockIdx.x * 4 + w;                  // 0..16383
    int b = gw >> 12;
    int m = gw & (M_ - 1);

    // zero bitmap: each lane clears 32 B
    *(uint4*)&bm[lane * 8]     = make_uint4(0u, 0u, 0u, 0u);
    *(uint4*)&bm[lane * 8 + 4] = make_uint4(0u, 0u, 0u, 0u);
    if (lane == 0) bcAll[w] = 0;

    size_t qb = ((size_t)b * M_ + m) * 3;
    float qx = newxyz[qb + 0], qy = newxyz[qb + 1], qz = newxyz[qb + 2];
    float qq = __fadd_rn(__fadd_rn(__fmul_rn(qx, qx), __fmul_rn(qy, qy)), __fmul_rn(qz, qz));
    int cx = cellof(qx), cy = cellof(qy), cz = cellof(qz);
    const float4* sp  = spts + (size_t)b * N_;
    const int*    sid = ssid + b * N_;
    const int*    st  = start + b * CSTRIDE;
    int x0 = cx > 0 ? cx - 1 : 0;
    int x1 = cx < GDIM - 1 ? cx + 1 : GDIM - 1;

    // lanes 0..8 prefetch the 9 row ranges (dz=lane/3-1, dy=lane%3-1)
    int sv = 0, ev = 0;
    if (lane < 9) {
        int dzi = lane / 3, dyi = lane - dzi * 3;
        int nz = cz + dzi - 1, ny = cy + dyi - 1;
        if ((unsigned)nz < GDIM && (unsigned)ny < GDIM) {
            int rowb = (nz << 10) | (ny << 5);
            sv = st[rowb | x0];
            ev = st[(rowb | x1) + 1];
        }
    }
    __builtin_amdgcn_wave_barrier();

    #pragma unroll 1
    for (int j = 0; j < 9; ++j) {
        int s = __shfl(sv, j);
        int e = __shfl(ev, j);
        for (int i = s + lane; i < e; i += 64) {
            float4 P = sp[i];
            float dot = __fmaf_rn(qz, P.z, __fmaf_rn(qy, P.y, __fmul_rn(qx, P.x)));
            float d2  = __fsub_rn(__fadd_rn(qq, P.w), __fmul_rn(2.0f, dot));
            if (d2 < R2_) {
                int o = sid[i];
                atomicOr(&bm[o >> 5], 1u << (o & 31));
            }
        }
    }
    __builtin_amdgcn_wave_barrier();

    // selection: lane owns dwords 8*lane .. 8*lane+7 (index-contiguous)
    uint4 a = *(const uint4*)&bm[lane * 8];
    uint4 c = *(const uint4*)&bm[lane * 8 + 4];
    unsigned int wds[8] = {a.x, a.y, a.z, a.w, c.x, c.y, c.z, c.w};
    int tl = 0;
    #pragma unroll
    for (int j = 0; j < 8; ++j) tl += __popc(wds[j]);
    int pre = tl;
    #pragma unroll
    for (int o = 1; o < 64; o <<= 1) { int u = __shfl_up(pre, o); if (lane >= o) pre += u; }
    int cnt = __shfl(pre, 63);
    int r = pre - tl;                       // global rank of this lane's first set bit
    int* outp = idx + ((size_t)b * M_ + m) * S_;
    int basei = lane << 8;                  // lane*8 dwords * 32 bits
    #pragma unroll
    for (int wd = 0; wd < 8; ++wd) {
        if (r >= S_) break;
        unsigned int bits = wds[wd];
        while (bits && r < S_) {
            int bpos = __builtin_ctz(bits);
            bits &= bits - 1;
            int gidx = basei + (wd << 5) + bpos;
            if (r == 0) bcAll[w] = gidx;
            outp[r] = gidx;
            ++r;
        }
    }
    __builtin_amdgcn_wave_barrier();
    int firstv = bcAll[w];
    if (lane < S_ && lane >= cnt) outp[lane] = firstv;
}

// A2: transpose features (B,C,N) -> (B,N,C)  [runs AFTER ball query: overwrites grid arrays]
__global__ __launch_bounds__(256) void transpose_feat(const float* __restrict__ f,
                                                      float* __restrict__ ft) {
    __shared__ float tile[64][65];
    int b  = blockIdx.x >> 8;
    int n0 = (blockIdx.x & 255) << 6;
    int tid  = threadIdx.x;
    int lane = tid & 63;
    int grp  = tid >> 6;
    #pragma unroll
    for (int r = 0; r < 16; ++r) {
        int c = r * 4 + grp;
        tile[c][lane] = f[((size_t)b * C_ + c) * N_ + n0 + lane];
    }
    __syncthreads();
    #pragma unroll
    for (int r = 0; r < 16; ++r) {
        int nl = r * 4 + grp;
        ft[((size_t)b * N_ + n0 + nl) * C_ + lane] = tile[lane][nl];
    }
}

// C: gather + assemble output (B, 67, M, S). One block per (b,m).
__global__ __launch_bounds__(256) void group_out(const float4* __restrict__ xyz4,
                                                 const float* __restrict__ ft,
                                                 const float* __restrict__ newxyz,
                                                 const int* __restrict__ idx,
                                                 float* __restrict__ out) {
    __shared__ int   sidx[32];
    __shared__ float q[3];
    int tid = threadIdx.x;
    int b   = blockIdx.x >> 12;
    int m   = blockIdx.x & 4095;
    if (tid < 32) sidx[tid] = idx[((size_t)b * M_ + m) * S_ + tid];
    if (tid < 3)  q[tid]    = newxyz[((size_t)b * M_ + m) * 3 + tid];
    __syncthreads();

    int s  = tid & 31;
    int c8 = tid >> 5;
    int p  = sidx[s];

    const float* fp = ft + ((size_t)b * N_ + p) * C_ + c8 * 8;
    float4 v0 = *(const float4*)(fp);
    float4 v1 = *(const float4*)(fp + 4);

    const size_t st = (size_t)M_ * S_;
    size_t ob = (((size_t)b * 67 + 3 + c8 * 8) * M_ + m) * S_ + s;
    out[ob + 0 * st] = v0.x;
    out[ob + 1 * st] = v0.y;
    out[ob + 2 * st] = v0.z;
    out[ob + 3 * st] = v0.w;
    out[ob + 4 * st] = v1.x;
    out[ob + 5 * st] = v1.y;
    out[ob + 6 * st] = v1.z;
    out[ob + 7 * st] = v1.w;

    if (tid < 32) {
        float4 P = xyz4[(size_t)b * N_ + p];
        size_t xb = (((size_t)b * 67 + 0) * M_ + m) * S_ + s;
        out[xb + 0 * st] = P.x - q[0];
        out[xb + 1 * st] = P.y - q[1];
        out[xb + 2 * st] = P.z - q[2];
    }
}

extern "C" void kernel_launch(void* const* d_in, const int* in_sizes, int n_in,
                              void* d_out, int out_size, void* d_ws, size_t ws_size,
                              hipStream_t stream) {
    const float* xyz    = (const float*)d_in[0];   // (B, N, 3)
    const float* newxyz = (const float*)d_in[1];   // (B, M, 3)
    const float* feat   = (const float*)d_in[2];   // (B, C, N)
    float* out = (float*)d_out;                    // (B, 67, M, S)

    char* ws = (char*)d_ws;
    float4* xyz4  = (float4*)(ws + OFF_XYZ4);
    float*  ft    = (float*)(ws + OFF_FT);
    int*    idxb  = (int*)(ws + OFF_IDX);
    int*    startc= (int*)(ws + OFF_START);
    int*    curc  = (int*)(ws + OFF_CUR);
    float4* spts  = (float4*)(ws + OFF_SPTS);
    int*    ssid  = (int*)(ws + OFF_SSID);

    hipMemsetAsync(curc, 0, (size_t)B_ * CSTRIDE * sizeof(int), stream);
    pack_hist     <<<(B_ * N_) / 256, 256, 0, stream>>>(xyz, xyz4, curc);
    scan_cells    <<<B_, 1024, 0, stream>>>(curc, startc);
    scatter_pts   <<<(B_ * N_) / 256, 256, 0, stream>>>(xyz4, curc, spts, ssid);
    ball_query_grid<<<(B_ * M_) / 4, 256, 0, stream>>>(spts, ssid, startc, newxyz, idxb);
    transpose_feat<<<B_ * (N_ / 64), 256, 0, stream>>>(feat, ft);
    group_out     <<<B_ * M_, 256, 0, stream>>>(xyz4, ft, newxyz, idxb, out);
}

// Round 8
// 220.594 us; speedup vs baseline: 1.3750x; 1.0397x over previous
//
#include <hip/hip_runtime.h>
#include <stdint.h>

#define B_ 4
#define N_ 16384
#define M_ 4096
#define C_ 64
#define S_ 32
#define R2_ 0.16f   // float(0.4*0.4)
#define GDIM 32
#define CELLS 32768       // 32^3 cells per batch, edge 0.5 over [-8, 8)
#define CSTRIDE 32772     // padded per-batch stride (>= CELLS+1)

// ---- workspace layout (all disjoint now, ~19.3 MB total) ----
// xyz4:  [B][N] float4 {x,y,z,pp}       @ 0      (1 MB)
// ft:    [B][N][C] float (transposed)   @ 1 MB   (16 MB)
// start: [B][CSTRIDE] int               @ 17 MB  (0.5 MB)
// cur:   [B][CSTRIDE] int                        (0.5 MB)
// spts:  [B][N] float4 (cell-sorted)             (1 MB)
// ssid:  [B][N] int (orig index)                 (0.25 MB)
static const size_t OFF_XYZ4  = 0;
static const size_t OFF_FT    = (size_t)B_ * N_ * 4 * sizeof(float);
static const size_t OFF_START = OFF_FT + (size_t)B_ * N_ * C_ * sizeof(float);
static const size_t OFF_CUR   = OFF_START + (size_t)B_ * CSTRIDE * sizeof(int);
static const size_t OFF_SPTS  = OFF_CUR + (size_t)B_ * CSTRIDE * sizeof(int);
static const size_t OFF_SSID  = OFF_SPTS + (size_t)B_ * N_ * 4 * sizeof(float);

__device__ __forceinline__ int cellof(float v) {
    int c = (int)floorf((v + 8.0f) * 2.0f);   // edge 0.5; coverage margin 0.5 > r
    return c < 0 ? 0 : (c > GDIM - 1 ? GDIM - 1 : c);
}

// A1+G1 fused: pack xyz into float4 {x,y,z,pp} (pp per-op rounded, bit-exact vs ref)
// and histogram cells. cur[] zeroed by hipMemsetAsync beforehand.
__global__ __launch_bounds__(256) void pack_hist(const float* __restrict__ xyz,
                                                 float4* __restrict__ xyz4,
                                                 int* __restrict__ cur) {
    int i = blockIdx.x * 256 + threadIdx.x;       // [0, B*N)
    int b = i >> 14;
    float x = xyz[3 * i + 0];
    float y = xyz[3 * i + 1];
    float z = xyz[3 * i + 2];
    float pp = __fadd_rn(__fadd_rn(__fmul_rn(x, x), __fmul_rn(y, y)), __fmul_rn(z, z));
    xyz4[i] = make_float4(x, y, z, pp);
    int cid = (cellof(z) << 10) | (cellof(y) << 5) | cellof(x);
    atomicAdd(&cur[b * CSTRIDE + cid], 1);
}

// G2: exclusive scan of 32768 cell counts per batch (one block per batch).
// Wave-shuffle prefix + single cross-wave pass -> 2 barriers.
// Writes start[] (+ sentinel start[CELLS]=N) and resets cur[] to start.
__global__ __launch_bounds__(1024) void scan_cells(int* __restrict__ cur,
                                                   int* __restrict__ start) {
    __shared__ int ls[16];                 // per-wave totals
    int b = blockIdx.x, t = threadIdx.x;
    int lane = t & 63, w = t >> 6;         // 16 waves
    int* cb = cur + b * CSTRIDE;
    int* sb = start + b * CSTRIDE;
    int base = t * 32;                     // 1024 threads x 32 cells = 32768
    int loc[32]; int tot = 0;
    #pragma unroll
    for (int j = 0; j < 32; ++j) { loc[j] = cb[base + j]; tot += loc[j]; }
    int pre = tot;
    #pragma unroll
    for (int o = 1; o < 64; o <<= 1) { int u = __shfl_up(pre, o); if (lane >= o) pre += u; }
    if (lane == 63) ls[w] = pre;           // wave total
    __syncthreads();
    if (t < 16) {
        int v = ls[t];
        int p16 = v;
        #pragma unroll
        for (int o = 1; o < 16; o <<= 1) { int u = __shfl_up(p16, o); if (t >= o) p16 += u; }
        ls[t] = p16 - v;                   // exclusive wave offset
    }
    __syncthreads();
    int run = ls[w] + (pre - tot);         // exclusive prefix for this thread's span
    #pragma unroll
    for (int j = 0; j < 32; ++j) { sb[base + j] = run; cb[base + j] = run; run += loc[j]; }
    if (t == 0) sb[CELLS] = N_;
}

// G3: scatter points into cell-sorted order (intra-cell order irrelevant; selection sorts by index)
__global__ __launch_bounds__(256) void scatter_pts(const float4* __restrict__ xyz4,
                                                   int* __restrict__ cur,
                                                   float4* __restrict__ spts,
                                                   int* __restrict__ ssid) {
    int i = blockIdx.x * 256 + threadIdx.x;       // [0, B*N)
    int b = i >> 14, n = i & (N_ - 1);
    float4 P = xyz4[i];
    int cid = (cellof(P.z) << 10) | (cellof(P.y) << 5) | cellof(P.x);
    int pos = atomicAdd(&cur[b * CSTRIDE + cid], 1);
    spts[(size_t)b * N_ + pos] = P;
    ssid[b * N_ + pos] = n;
}

// A2: transpose features (B,C,N) -> (B,N,C)  [must precede bq_group]
__global__ __launch_bounds__(256) void transpose_feat(const float* __restrict__ f,
                                                      float* __restrict__ ft) {
    __shared__ float tile[64][65];
    int b  = blockIdx.x >> 8;
    int n0 = (blockIdx.x & 255) << 6;
    int tid  = threadIdx.x;
    int lane = tid & 63;
    int grp  = tid >> 6;
    #pragma unroll
    for (int r = 0; r < 16; ++r) {
        int c = r * 4 + grp;
        tile[c][lane] = f[((size_t)b * C_ + c) * N_ + n0 + lane];
    }
    __syncthreads();
    #pragma unroll
    for (int r = 0; r < 16; ++r) {
        int nl = r * 4 + grp;
        ft[((size_t)b * N_ + n0 + nl) * C_ + lane] = tile[lane][nl];
    }
}

// B+C fused: grid ball query + gather + output assembly. One wave per query.
// Scan phase: in-ball hits set bits in a 16384-bit LDS bitmap (index-ordered).
// Selection: one popcount-prefix pass emits the 32 smallest indices ascending
// (pad = rank-0 index, 0 if none) into LDS (bitmap storage reused).
// Gather phase: lane (s=lane&31, half=lane>>5) reads half of sample s's 256 B
// feature row and writes 32 channel values + (half 0) the centered xyz.
// Distance chain and centering bit-exact vs reference.
__global__ __launch_bounds__(256) void bq_group(const float4* __restrict__ spts,
                                                const int* __restrict__ ssid,
                                                const int* __restrict__ start,
                                                const float* __restrict__ newxyz,
                                                const float4* __restrict__ xyz4,
                                                const float* __restrict__ ft,
                                                float* __restrict__ out) {
    __shared__ unsigned int bmAll[4][512];   // 2 KB bitmap per wave (reused as sel[])
    __shared__ int bcAll[4];                 // rank-0 broadcast per wave
    int tid = threadIdx.x, lane = tid & 63, w = tid >> 6;
    unsigned int* bm = bmAll[w];
    int gw = blockIdx.x * 4 + w;                  // 0..16383
    int b = gw >> 12;
    int m = gw & (M_ - 1);

    // zero bitmap: each lane clears 32 B
    *(uint4*)&bm[lane * 8]     = make_uint4(0u, 0u, 0u, 0u);
    *(uint4*)&bm[lane * 8 + 4] = make_uint4(0u, 0u, 0u, 0u);
    if (lane == 0) bcAll[w] = 0;

    size_t qb = ((size_t)b * M_ + m) * 3;
    float qx = newxyz[qb + 0], qy = newxyz[qb + 1], qz = newxyz[qb + 2];
    float qq = __fadd_rn(__fadd_rn(__fmul_rn(qx, qx), __fmul_rn(qy, qy)), __fmul_rn(qz, qz));
    int cx = cellof(qx), cy = cellof(qy), cz = cellof(qz);
    const float4* sp  = spts + (size_t)b * N_;
    const int*    sid = ssid + b * N_;
    const int*    st  = start + b * CSTRIDE;
    int x0 = cx > 0 ? cx - 1 : 0;
    int x1 = cx < GDIM - 1 ? cx + 1 : GDIM - 1;

    // lanes 0..8 prefetch the 9 row ranges (dz=lane/3-1, dy=lane%3-1)
    int sv = 0, ev = 0;
    if (lane < 9) {
        int dzi = lane / 3, dyi = lane - dzi * 3;
        int nz = cz + dzi - 1, ny = cy + dyi - 1;
        if ((unsigned)nz < GDIM && (unsigned)ny < GDIM) {
            int rowb = (nz << 10) | (ny << 5);
            sv = st[rowb | x0];
            ev = st[(rowb | x1) + 1];
        }
    }
    __builtin_amdgcn_wave_barrier();

    #pragma unroll 1
    for (int j = 0; j < 9; ++j) {
        int s = __shfl(sv, j);
        int e = __shfl(ev, j);
        for (int i = s + lane; i < e; i += 64) {
            float4 P = sp[i];
            float dot = __fmaf_rn(qz, P.z, __fmaf_rn(qy, P.y, __fmul_rn(qx, P.x)));
            float d2  = __fsub_rn(__fadd_rn(qq, P.w), __fmul_rn(2.0f, dot));
            if (d2 < R2_) {
                int o = sid[i];
                atomicOr(&bm[o >> 5], 1u << (o & 31));
            }
        }
    }
    __builtin_amdgcn_wave_barrier();

    // selection: lane owns dwords 8*lane .. 8*lane+7 (index-contiguous)
    uint4 a = *(const uint4*)&bm[lane * 8];
    uint4 c = *(const uint4*)&bm[lane * 8 + 4];
    unsigned int wds[8] = {a.x, a.y, a.z, a.w, c.x, c.y, c.z, c.w};
    int tl = 0;
    #pragma unroll
    for (int j = 0; j < 8; ++j) tl += __popc(wds[j]);
    int pre = tl;
    #pragma unroll
    for (int o = 1; o < 64; o <<= 1) { int u = __shfl_up(pre, o); if (lane >= o) pre += u; }
    int cnt = __shfl(pre, 63);
    int r = pre - tl;                       // global rank of this lane's first set bit
    int basei = lane << 8;                  // lane*8 dwords * 32 bits
    __builtin_amdgcn_wave_barrier();        // all bitmap loads done before reuse as sel[]
    int* sel = (int*)bm;                    // first 32 dwords reused as sel[32]
    #pragma unroll
    for (int wd = 0; wd < 8; ++wd) {
        if (r >= S_) break;
        unsigned int bits = wds[wd];
        while (bits && r < S_) {
            int bpos = __builtin_ctz(bits);
            bits &= bits - 1;
            int gidx = basei + (wd << 5) + bpos;
            if (r == 0) bcAll[w] = gidx;
            sel[r] = gidx;
            ++r;
        }
    }
    __builtin_amdgcn_wave_barrier();
    if (lane < S_ && lane >= cnt) sel[lane] = bcAll[w];   // pad with rank-0 index
    __builtin_amdgcn_wave_barrier();

    // gather + write: lane = (s, half)
    int s    = lane & 31;
    int half = lane >> 5;
    int p    = sel[s];
    const float* fp = ft + (((size_t)b * N_ + p) << 6) + half * 32;
    float4 v[8];
    #pragma unroll
    for (int j = 0; j < 8; ++j) v[j] = *(const float4*)(fp + j * 4);

    const size_t cst = (size_t)M_ * S_;     // stride between channel planes
    size_t ob = (((size_t)b * 67 + 3 + half * 32) * M_ + m) * S_ + s;
    #pragma unroll
    for (int j = 0; j < 8; ++j) {
        out[ob + (4 * j + 0) * cst] = v[j].x;
        out[ob + (4 * j + 1) * cst] = v[j].y;
        out[ob + (4 * j + 2) * cst] = v[j].z;
        out[ob + (4 * j + 3) * cst] = v[j].w;
    }
    if (half == 0) {
        float4 P = xyz4[(size_t)b * N_ + p];
        size_t xb = (((size_t)b * 67 + 0) * M_ + m) * S_ + s;
        out[xb + 0 * cst] = P.x - qx;
        out[xb + 1 * cst] = P.y - qy;
        out[xb + 2 * cst] = P.z - qz;
    }
}

extern "C" void kernel_launch(void* const* d_in, const int* in_sizes, int n_in,
                              void* d_out, int out_size, void* d_ws, size_t ws_size,
                              hipStream_t stream) {
    const float* xyz    = (const float*)d_in[0];   // (B, N, 3)
    const float* newxyz = (const float*)d_in[1];   // (B, M, 3)
    const float* feat   = (const float*)d_in[2];   // (B, C, N)
    float* out = (float*)d_out;                    // (B, 67, M, S)

    char* ws = (char*)d_ws;
    float4* xyz4  = (float4*)(ws + OFF_XYZ4);
    float*  ft    = (float*)(ws + OFF_FT);
    int*    startc= (int*)(ws + OFF_START);
    int*    curc  = (int*)(ws + OFF_CUR);
    float4* spts  = (float4*)(ws + OFF_SPTS);
    int*    ssid  = (int*)(ws + OFF_SSID);

    hipMemsetAsync(curc, 0, (size_t)B_ * CSTRIDE * sizeof(int), stream);
    pack_hist     <<<(B_ * N_) / 256, 256, 0, stream>>>(xyz, xyz4, curc);
    scan_cells    <<<B_, 1024, 0, stream>>>(curc, startc);
    scatter_pts   <<<(B_ * N_) / 256, 256, 0, stream>>>(xyz4, curc, spts, ssid);
    transpose_feat<<<B_ * (N_ / 64), 256, 0, stream>>>(feat, ft);
    bq_group      <<<(B_ * M_) / 4, 256, 0, stream>>>(spts, ssid, startc, newxyz,
                                                      xyz4, ft, out);
}

// Round 10
// 218.147 us; speedup vs baseline: 1.3904x; 1.0112x over previous
//
#include <hip/hip_runtime.h>
#include <stdint.h>

#define B_ 4
#define N_ 16384
#define M_ 4096
#define C_ 64
#define S_ 32
#define R2_ 0.16f   // float(0.4*0.4)
#define GDIM 32
#define CELLS 32768       // 32^3 cells per batch, edge 0.5 over [-8, 8)
#define CSTRIDE 32772     // padded per-batch stride (>= CELLS+1)

// ---- workspace layout (all disjoint, ~19.3 MB total) ----
static const size_t OFF_XYZ4  = 0;
static const size_t OFF_FT    = (size_t)B_ * N_ * 4 * sizeof(float);
static const size_t OFF_START = OFF_FT + (size_t)B_ * N_ * C_ * sizeof(float);
static const size_t OFF_CUR   = OFF_START + (size_t)B_ * CSTRIDE * sizeof(int);
static const size_t OFF_SPTS  = OFF_CUR + (size_t)B_ * CSTRIDE * sizeof(int);
static const size_t OFF_SSID  = OFF_SPTS + (size_t)B_ * N_ * 4 * sizeof(float);

__device__ __forceinline__ int cellof(float v) {
    int c = (int)floorf((v + 8.0f) * 2.0f);   // edge 0.5; coverage margin 0.5 > r
    return c < 0 ? 0 : (c > GDIM - 1 ? GDIM - 1 : c);
}

// K1: blocks [0,256): pack xyz -> float4 {x,y,z,pp} (pp per-op rounded, bit-exact)
//     + cell histogram (cur[] pre-zeroed by memset).
//     blocks [256,1280): transpose features (B,C,N) -> (B,N,C).
__global__ __launch_bounds__(256) void pack_hist_transpose(const float* __restrict__ xyz,
                                                           float4* __restrict__ xyz4,
                                                           int* __restrict__ cur,
                                                           const float* __restrict__ f,
                                                           float* __restrict__ ft) {
    if (blockIdx.x < 256) {
        int i = blockIdx.x * 256 + threadIdx.x;       // [0, B*N)
        int b = i >> 14;
        float x = __builtin_nontemporal_load(&xyz[3 * i + 0]);
        float y = __builtin_nontemporal_load(&xyz[3 * i + 1]);
        float z = __builtin_nontemporal_load(&xyz[3 * i + 2]);
        float pp = __fadd_rn(__fadd_rn(__fmul_rn(x, x), __fmul_rn(y, y)), __fmul_rn(z, z));
        xyz4[i] = make_float4(x, y, z, pp);
        int cid = (cellof(z) << 10) | (cellof(y) << 5) | cellof(x);
        atomicAdd(&cur[b * CSTRIDE + cid], 1);
    } else {
        __shared__ float tile[64][65];
        int blk = blockIdx.x - 256;
        int b  = blk >> 8;
        int n0 = (blk & 255) << 6;
        int tid  = threadIdx.x;
        int lane = tid & 63;
        int grp  = tid >> 6;                // 0..3
        #pragma unroll
        for (int r = 0; r < 16; ++r) {
            int c = r * 4 + grp;
            tile[c][lane] = __builtin_nontemporal_load(&f[((size_t)b * C_ + c) * N_ + n0 + lane]);
        }
        __syncthreads();
        #pragma unroll
        for (int r = 0; r < 16; ++r) {
            int nl = r * 4 + grp;
            ft[((size_t)b * N_ + n0 + nl) * C_ + lane] = tile[lane][nl];
        }
    }
}

// G2: exclusive scan of 32768 cell counts per batch (one block per batch).
__global__ __launch_bounds__(1024) void scan_cells(int* __restrict__ cur,
                                                   int* __restrict__ start) {
    __shared__ int ls[16];                 // per-wave totals
    int b = blockIdx.x, t = threadIdx.x;
    int lane = t & 63, w = t >> 6;         // 16 waves
    int* cb = cur + b * CSTRIDE;
    int* sb = start + b * CSTRIDE;
    int base = t * 32;                     // 1024 threads x 32 cells = 32768
    int loc[32]; int tot = 0;
    #pragma unroll
    for (int j = 0; j < 32; ++j) { loc[j] = cb[base + j]; tot += loc[j]; }
    int pre = tot;
    #pragma unroll
    for (int o = 1; o < 64; o <<= 1) { int u = __shfl_up(pre, o); if (lane >= o) pre += u; }
    if (lane == 63) ls[w] = pre;           // wave total
    __syncthreads();
    if (t < 16) {
        int v = ls[t];
        int p16 = v;
        #pragma unroll
        for (int o = 1; o < 16; o <<= 1) { int u = __shfl_up(p16, o); if (t >= o) p16 += u; }
        ls[t] = p16 - v;                   // exclusive wave offset
    }
    __syncthreads();
    int run = ls[w] + (pre - tot);         // exclusive prefix for this thread's span
    #pragma unroll
    for (int j = 0; j < 32; ++j) { sb[base + j] = run; cb[base + j] = run; run += loc[j]; }
    if (t == 0) sb[CELLS] = N_;
}

// G3: scatter points into cell-sorted order
__global__ __launch_bounds__(256) void scatter_pts(const float4* __restrict__ xyz4,
                                                   int* __restrict__ cur,
                                                   float4* __restrict__ spts,
                                                   int* __restrict__ ssid) {
    int i = blockIdx.x * 256 + threadIdx.x;       // [0, B*N)
    int b = i >> 14, n = i & (N_ - 1);
    float4 P = xyz4[i];
    int cid = (cellof(P.z) << 10) | (cellof(P.y) << 5) | cellof(P.x);
    int pos = atomicAdd(&cur[b * CSTRIDE + cid], 1);
    spts[(size_t)b * N_ + pos] = P;
    ssid[b * N_ + pos] = n;
}

// B+C fused: grid ball query + gather + output assembly. One wave per query.
// Per-(dz,dy)-row conservative pruning: skip rows whose slab min-distance
// exceeds r (+1e-3 slack), tighten x-cell range to qx +- sqrt(r^2 - dmin^2).
// Border slabs extended to infinity so coordinate-clamped points are safe.
// Bitmap selection identical to R8 (absmax 0.0 proven). Output via nt-stores.
__global__ __launch_bounds__(256) void bq_group(const float4* __restrict__ spts,
                                                const int* __restrict__ ssid,
                                                const int* __restrict__ start,
                                                const float* __restrict__ newxyz,
                                                const float4* __restrict__ xyz4,
                                                const float* __restrict__ ft,
                                                float* __restrict__ out) {
    __shared__ unsigned int bmAll[4][512];   // 2 KB bitmap per wave (reused as sel[])
    __shared__ int bcAll[4];                 // rank-0 broadcast per wave
    int tid = threadIdx.x, lane = tid & 63, w = tid >> 6;
    unsigned int* bm = bmAll[w];
    int gw = blockIdx.x * 4 + w;                  // 0..16383
    int b = gw >> 12;
    int m = gw & (M_ - 1);

    // zero bitmap: each lane clears 32 B
    *(uint4*)&bm[lane * 8]     = make_uint4(0u, 0u, 0u, 0u);
    *(uint4*)&bm[lane * 8 + 4] = make_uint4(0u, 0u, 0u, 0u);
    if (lane == 0) bcAll[w] = 0;

    size_t qb = ((size_t)b * M_ + m) * 3;
    float qx = newxyz[qb + 0], qy = newxyz[qb + 1], qz = newxyz[qb + 2];
    float qq = __fadd_rn(__fadd_rn(__fmul_rn(qx, qx), __fmul_rn(qy, qy)), __fmul_rn(qz, qz));
    int cx = cellof(qx), cy = cellof(qy), cz = cellof(qz);
    const float4* sp  = spts + (size_t)b * N_;
    const int*    sid = ssid + b * N_;
    const int*    st  = start + b * CSTRIDE;
    int x0 = cx > 0 ? cx - 1 : 0;
    int x1 = cx < GDIM - 1 ? cx + 1 : GDIM - 1;

    // lanes 0..8: row (dz=lane/3-1, dy=lane%3-1) with conservative pruning
    int sv = 0, ev = 0;
    if (lane < 9) {
        int dzi = lane / 3, dyi = lane - dzi * 3;
        int nz = cz + dzi - 1, ny = cy + dyi - 1;
        if ((unsigned)nz < GDIM && (unsigned)ny < GDIM) {
            float zlo = (nz == 0)        ? -1e30f : -8.0f + 0.5f * nz;
            float zhi = (nz == GDIM - 1) ?  1e30f : -8.0f + 0.5f * (nz + 1);
            float ylo = (ny == 0)        ? -1e30f : -8.0f + 0.5f * ny;
            float yhi = (ny == GDIM - 1) ?  1e30f : -8.0f + 0.5f * (ny + 1);
            float dz = fmaxf(fmaxf(zlo - qz, qz - zhi), 0.0f);
            float dy = fmaxf(fmaxf(ylo - qy, qy - yhi), 0.0f);
            float rem = R2_ + 1e-3f - dz * dz - dy * dy;
            if (rem > 0.0f) {
                float rx = sqrtf(rem) + 1e-3f;
                int xl = (int)floorf((qx - rx + 8.0f) * 2.0f);
                int xh = (int)floorf((qx + rx + 8.0f) * 2.0f);
                xl = xl < 0 ? 0 : xl;  xh = xh > GDIM - 1 ? GDIM - 1 : xh;
                xl = xl > x0 ? xl : x0;
                xh = xh < x1 ? xh : x1;
                if (xl <= xh) {
                    int rowb = (nz << 10) | (ny << 5);
                    sv = st[rowb | xl];
                    ev = st[(rowb | xh) + 1];
                }
            }
        }
    }
    __builtin_amdgcn_wave_barrier();

    #pragma unroll 1
    for (int j = 0; j < 9; ++j) {
        int s = __shfl(sv, j);
        int e = __shfl(ev, j);
        for (int i = s + lane; i < e; i += 64) {
            float4 P = sp[i];
            int o = sid[i];                        // unconditional: coalesced, no dep
            float dot = __fmaf_rn(qz, P.z, __fmaf_rn(qy, P.y, __fmul_rn(qx, P.x)));
            float d2  = __fsub_rn(__fadd_rn(qq, P.w), __fmul_rn(2.0f, dot));
            if (d2 < R2_) {
                atomicOr(&bm[o >> 5], 1u << (o & 31));
            }
        }
    }
    __builtin_amdgcn_wave_barrier();

    // selection: lane owns dwords 8*lane .. 8*lane+7 (index-contiguous)
    uint4 a = *(const uint4*)&bm[lane * 8];
    uint4 c = *(const uint4*)&bm[lane * 8 + 4];
    unsigned int wds[8] = {a.x, a.y, a.z, a.w, c.x, c.y, c.z, c.w};
    int tl = 0;
    #pragma unroll
    for (int j = 0; j < 8; ++j) tl += __popc(wds[j]);
    int pre = tl;
    #pragma unroll
    for (int o = 1; o < 64; o <<= 1) { int u = __shfl_up(pre, o); if (lane >= o) pre += u; }
    int cnt = __shfl(pre, 63);
    int r = pre - tl;                       // global rank of this lane's first set bit
    int basei = lane << 8;                  // lane*8 dwords * 32 bits
    __builtin_amdgcn_wave_barrier();        // all bitmap loads done before reuse as sel[]
    int* sel = (int*)bm;                    // first 32 dwords reused as sel[32]
    #pragma unroll
    for (int wd = 0; wd < 8; ++wd) {
        if (r >= S_) break;
        unsigned int bits = wds[wd];
        while (bits && r < S_) {
            int bpos = __builtin_ctz(bits);
            bits &= bits - 1;
            int gidx = basei + (wd << 5) + bpos;
            if (r == 0) bcAll[w] = gidx;
            sel[r] = gidx;
            ++r;
        }
    }
    __builtin_amdgcn_wave_barrier();
    if (lane < S_ && lane >= cnt) sel[lane] = bcAll[w];   // pad with rank-0 index
    __builtin_amdgcn_wave_barrier();

    // gather + write: lane = (s, half); output stores nontemporal (keep ft in L2)
    int s    = lane & 31;
    int half = lane >> 5;
    int p    = sel[s];
    const float* fp = ft + (((size_t)b * N_ + p) << 6) + half * 32;
    float4 v[8];
    #pragma unroll
    for (int j = 0; j < 8; ++j) v[j] = *(const float4*)(fp + j * 4);

    const size_t cst = (size_t)M_ * S_;     // stride between channel planes
    size_t ob = (((size_t)b * 67 + 3 + half * 32) * M_ + m) * S_ + s;
    #pragma unroll
    for (int j = 0; j < 8; ++j) {
        __builtin_nontemporal_store(v[j].x, &out[ob + (4 * j + 0) * cst]);
        __builtin_nontemporal_store(v[j].y, &out[ob + (4 * j + 1) * cst]);
        __builtin_nontemporal_store(v[j].z, &out[ob + (4 * j + 2) * cst]);
        __builtin_nontemporal_store(v[j].w, &out[ob + (4 * j + 3) * cst]);
    }
    if (half == 0) {
        float4 P = xyz4[(size_t)b * N_ + p];
        size_t xb = (((size_t)b * 67 + 0) * M_ + m) * S_ + s;
        __builtin_nontemporal_store(P.x - qx, &out[xb + 0 * cst]);
        __builtin_nontemporal_store(P.y - qy, &out[xb + 1 * cst]);
        __builtin_nontemporal_store(P.z - qz, &out[xb + 2 * cst]);
    }
}

extern "C" void kernel_launch(void* const* d_in, const int* in_sizes, int n_in,
                              void* d_out, int out_size, void* d_ws, size_t ws_size,
                              hipStream_t stream) {
    const float* xyz    = (const float*)d_in[0];   // (B, N, 3)
    const float* newxyz = (const float*)d_in[1];   // (B, M, 3)
    const float* feat   = (const float*)d_in[2];   // (B, C, N)
    float* out = (float*)d_out;                    // (B, 67, M, S)

    char* ws = (char*)d_ws;
    float4* xyz4  = (float4*)(ws + OFF_XYZ4);
    float*  ft    = (float*)(ws + OFF_FT);
    int*    startc= (int*)(ws + OFF_START);
    int*    curc  = (int*)(ws + OFF_CUR);
    float4* spts  = (float4*)(ws + OFF_SPTS);
    int*    ssid  = (int*)(ws + OFF_SSID);

    hipMemsetAsync(curc, 0, (size_t)B_ * CSTRIDE * sizeof(int), stream);
    pack_hist_transpose<<<256 + B_ * (N_ / 64), 256, 0, stream>>>(xyz, xyz4, curc, feat, ft);
    scan_cells    <<<B_, 1024, 0, stream>>>(curc, startc);
    scatter_pts   <<<(B_ * N_) / 256, 256, 0, stream>>>(xyz4, curc, spts, ssid);
    bq_group      <<<(B_ * M_) / 4, 256, 0, stream>>>(spts, ssid, startc, newxyz,
                                                      xyz4, ft, out);
}

// Round 11
// 216.617 us; speedup vs baseline: 1.4002x; 1.0071x over previous
//
#include <hip/hip_runtime.h>
#include <stdint.h>

#define B_ 4
#define N_ 16384
#define M_ 4096
#define C_ 64
#define S_ 32
#define R2_ 0.16f   // float(0.4*0.4)
#define GDIM 32
#define CELLS 32768       // 32^3 cells per batch, edge 0.5 over [-8, 8)
#define CSTRIDE 32772     // padded per-batch stride (>= CELLS+1)

// ---- workspace layout (all disjoint, ~19.3 MB total) ----
static const size_t OFF_XYZ4  = 0;
static const size_t OFF_FT    = (size_t)B_ * N_ * 4 * sizeof(float);
static const size_t OFF_START = OFF_FT + (size_t)B_ * N_ * C_ * sizeof(float);
static const size_t OFF_CUR   = OFF_START + (size_t)B_ * CSTRIDE * sizeof(int);
static const size_t OFF_SPTS  = OFF_CUR + (size_t)B_ * CSTRIDE * sizeof(int);
static const size_t OFF_SSID  = OFF_SPTS + (size_t)B_ * N_ * 4 * sizeof(float);

__device__ __forceinline__ int cellof(float v) {
    int c = (int)floorf((v + 8.0f) * 2.0f);   // edge 0.5; coverage margin 0.5 > r
    return c < 0 ? 0 : (c > GDIM - 1 ? GDIM - 1 : c);
}

// K1: blocks [0,256): pack xyz -> float4 {x,y,z,pp} (pp per-op rounded, bit-exact)
//     + cell histogram (cur[] pre-zeroed by memset).
//     blocks [256,1280): transpose features (B,C,N) -> (B,N,C).
__global__ __launch_bounds__(256) void pack_hist_transpose(const float* __restrict__ xyz,
                                                           float4* __restrict__ xyz4,
                                                           int* __restrict__ cur,
                                                           const float* __restrict__ f,
                                                           float* __restrict__ ft) {
    if (blockIdx.x < 256) {
        int i = blockIdx.x * 256 + threadIdx.x;       // [0, B*N)
        int b = i >> 14;
        float x = __builtin_nontemporal_load(&xyz[3 * i + 0]);
        float y = __builtin_nontemporal_load(&xyz[3 * i + 1]);
        float z = __builtin_nontemporal_load(&xyz[3 * i + 2]);
        float pp = __fadd_rn(__fadd_rn(__fmul_rn(x, x), __fmul_rn(y, y)), __fmul_rn(z, z));
        xyz4[i] = make_float4(x, y, z, pp);
        int cid = (cellof(z) << 10) | (cellof(y) << 5) | cellof(x);
        atomicAdd(&cur[b * CSTRIDE + cid], 1);
    } else {
        __shared__ float tile[64][65];
        int blk = blockIdx.x - 256;
        int b  = blk >> 8;
        int n0 = (blk & 255) << 6;
        int tid  = threadIdx.x;
        int lane = tid & 63;
        int grp  = tid >> 6;                // 0..3
        #pragma unroll
        for (int r = 0; r < 16; ++r) {
            int c = r * 4 + grp;
            tile[c][lane] = __builtin_nontemporal_load(&f[((size_t)b * C_ + c) * N_ + n0 + lane]);
        }
        __syncthreads();
        #pragma unroll
        for (int r = 0; r < 16; ++r) {
            int nl = r * 4 + grp;
            ft[((size_t)b * N_ + n0 + nl) * C_ + lane] = tile[lane][nl];
        }
    }
}

// G2: exclusive scan of 32768 cell counts per batch (one block per batch).
__global__ __launch_bounds__(1024) void scan_cells(int* __restrict__ cur,
                                                   int* __restrict__ start) {
    __shared__ int ls[16];                 // per-wave totals
    int b = blockIdx.x, t = threadIdx.x;
    int lane = t & 63, w = t >> 6;         // 16 waves
    int* cb = cur + b * CSTRIDE;
    int* sb = start + b * CSTRIDE;
    int base = t * 32;                     // 1024 threads x 32 cells = 32768
    int loc[32]; int tot = 0;
    #pragma unroll
    for (int j = 0; j < 32; ++j) { loc[j] = cb[base + j]; tot += loc[j]; }
    int pre = tot;
    #pragma unroll
    for (int o = 1; o < 64; o <<= 1) { int u = __shfl_up(pre, o); if (lane >= o) pre += u; }
    if (lane == 63) ls[w] = pre;           // wave total
    __syncthreads();
    if (t < 16) {
        int v = ls[t];
        int p16 = v;
        #pragma unroll
        for (int o = 1; o < 16; o <<= 1) { int u = __shfl_up(p16, o); if (t >= o) p16 += u; }
        ls[t] = p16 - v;                   // exclusive wave offset
    }
    __syncthreads();
    int run = ls[w] + (pre - tot);         // exclusive prefix for this thread's span
    #pragma unroll
    for (int j = 0; j < 32; ++j) { sb[base + j] = run; cb[base + j] = run; run += loc[j]; }
    if (t == 0) sb[CELLS] = N_;
}

// G3: scatter points into cell-sorted order
__global__ __launch_bounds__(256) void scatter_pts(const float4* __restrict__ xyz4,
                                                   int* __restrict__ cur,
                                                   float4* __restrict__ spts,
                                                   int* __restrict__ ssid) {
    int i = blockIdx.x * 256 + threadIdx.x;       // [0, B*N)
    int b = i >> 14, n = i & (N_ - 1);
    float4 P = xyz4[i];
    int cid = (cellof(P.z) << 10) | (cellof(P.y) << 5) | cellof(P.x);
    int pos = atomicAdd(&cur[b * CSTRIDE + cid], 1);
    spts[(size_t)b * N_ + pos] = P;
    ssid[b * N_ + pos] = n;
}

// B+C fused: grid ball query + gather + output assembly. One wave per query.
// XCD->batch pinning: blockIdx&7 selects the XCD (round-robin dispatch); XCD
// pair {2b,2b+1} handles only batch b, so ft/spts/ssid/start for that batch
// stay resident in the XCD's 4 MB L2. Bijective remap -> correctness-neutral.
// Scan: 9 pruned row-segments flattened into ONE full-lane loop; the 9
// (base, boundary) descriptors are wave-uniform -> hoisted to SGPRs.
// Bitmap selection identical to R8 (absmax 0.0 proven). Output via nt-stores.
__global__ __launch_bounds__(256) void bq_group(const float4* __restrict__ spts,
                                                const int* __restrict__ ssid,
                                                const int* __restrict__ start,
                                                const float* __restrict__ newxyz,
                                                const float4* __restrict__ xyz4,
                                                const float* __restrict__ ft,
                                                float* __restrict__ out) {
    __shared__ unsigned int bmAll[4][512];   // 2 KB bitmap per wave (reused as sel[])
    __shared__ int bcAll[4];                 // rank-0 broadcast per wave
    int tid = threadIdx.x, lane = tid & 63, w = tid >> 6;
    unsigned int* bm = bmAll[w];
    int xcd = blockIdx.x & 7;
    int b   = xcd >> 1;                           // batch pinned to XCD pair
    int iw  = ((blockIdx.x >> 3) << 1) | (xcd & 1);   // [0, 1024) within batch
    int m   = (iw << 2) | w;                      // query id within batch

    // zero bitmap: each lane clears 32 B
    *(uint4*)&bm[lane * 8]     = make_uint4(0u, 0u, 0u, 0u);
    *(uint4*)&bm[lane * 8 + 4] = make_uint4(0u, 0u, 0u, 0u);
    if (lane == 0) bcAll[w] = 0;

    size_t qb = ((size_t)b * M_ + m) * 3;
    float qx = newxyz[qb + 0], qy = newxyz[qb + 1], qz = newxyz[qb + 2];
    float qq = __fadd_rn(__fadd_rn(__fmul_rn(qx, qx), __fmul_rn(qy, qy)), __fmul_rn(qz, qz));
    int cx = cellof(qx), cy = cellof(qy), cz = cellof(qz);
    const float4* sp  = spts + (size_t)b * N_;
    const int*    sid = ssid + b * N_;
    const int*    st  = start + b * CSTRIDE;
    int x0 = cx > 0 ? cx - 1 : 0;
    int x1 = cx < GDIM - 1 ? cx + 1 : GDIM - 1;

    // lanes 0..8: row (dz=lane/3-1, dy=lane%3-1) with conservative slab pruning
    int sv = 0, ev = 0;
    if (lane < 9) {
        int dzi = lane / 3, dyi = lane - dzi * 3;
        int nz = cz + dzi - 1, ny = cy + dyi - 1;
        if ((unsigned)nz < GDIM && (unsigned)ny < GDIM) {
            float zlo = (nz == 0)        ? -1e30f : -8.0f + 0.5f * nz;
            float zhi = (nz == GDIM - 1) ?  1e30f : -8.0f + 0.5f * (nz + 1);
            float ylo = (ny == 0)        ? -1e30f : -8.0f + 0.5f * ny;
            float yhi = (ny == GDIM - 1) ?  1e30f : -8.0f + 0.5f * (ny + 1);
            float dz = fmaxf(fmaxf(zlo - qz, qz - zhi), 0.0f);
            float dy = fmaxf(fmaxf(ylo - qy, qy - yhi), 0.0f);
            float rem = R2_ + 1e-3f - dz * dz - dy * dy;
            if (rem > 0.0f) {
                float rx = sqrtf(rem) + 1e-3f;
                int xl = (int)floorf((qx - rx + 8.0f) * 2.0f);
                int xh = (int)floorf((qx + rx + 8.0f) * 2.0f);
                xl = xl < 0 ? 0 : xl;  xh = xh > GDIM - 1 ? GDIM - 1 : xh;
                xl = xl > x0 ? xl : x0;
                xh = xh < x1 ? xh : x1;
                if (xl <= xh) {
                    int rowb = (nz << 10) | (ny << 5);
                    sv = st[rowb | xl];
                    ev = st[(rowb | xh) + 1];
                }
            }
        }
    }
    // flatten: inclusive prefix of row lengths over lanes 0..8
    int len = ev - sv;
    int pfx = len;
    #pragma unroll
    for (int o = 1; o < 16; o <<= 1) { int u = __shfl_up(pfx, o); if (lane >= o) pfx += u; }
    int L    = __builtin_amdgcn_readfirstlane(__shfl(pfx, 8));   // total candidates
    int badj = sv - (pfx - len);          // sv_r - exclusive_prefix_r
    // wave-uniform row descriptors -> SGPRs (no VGPR pressure)
    int sb0 = __builtin_amdgcn_readfirstlane(__shfl(badj, 0));
    int sb1 = __builtin_amdgcn_readfirstlane(__shfl(badj, 1));
    int sb2 = __builtin_amdgcn_readfirstlane(__shfl(badj, 2));
    int sb3 = __builtin_amdgcn_readfirstlane(__shfl(badj, 3));
    int sb4 = __builtin_amdgcn_readfirstlane(__shfl(badj, 4));
    int sb5 = __builtin_amdgcn_readfirstlane(__shfl(badj, 5));
    int sb6 = __builtin_amdgcn_readfirstlane(__shfl(badj, 6));
    int sb7 = __builtin_amdgcn_readfirstlane(__shfl(badj, 7));
    int sb8 = __builtin_amdgcn_readfirstlane(__shfl(badj, 8));
    int se1 = __builtin_amdgcn_readfirstlane(__shfl(pfx, 0));
    int se2 = __builtin_amdgcn_readfirstlane(__shfl(pfx, 1));
    int se3 = __builtin_amdgcn_readfirstlane(__shfl(pfx, 2));
    int se4 = __builtin_amdgcn_readfirstlane(__shfl(pfx, 3));
    int se5 = __builtin_amdgcn_readfirstlane(__shfl(pfx, 4));
    int se6 = __builtin_amdgcn_readfirstlane(__shfl(pfx, 5));
    int se7 = __builtin_amdgcn_readfirstlane(__shfl(pfx, 6));
    int se8 = __builtin_amdgcn_readfirstlane(__shfl(pfx, 7));

    for (int t = lane; t < L; t += 64) {
        int off = sb0 + t;
        if (t >= se1) off = sb1 + t;
        if (t >= se2) off = sb2 + t;
        if (t >= se3) off = sb3 + t;
        if (t >= se4) off = sb4 + t;
        if (t >= se5) off = sb5 + t;
        if (t >= se6) off = sb6 + t;
        if (t >= se7) off = sb7 + t;
        if (t >= se8) off = sb8 + t;
        float4 P = sp[off];
        int o = sid[off];
        float dot = __fmaf_rn(qz, P.z, __fmaf_rn(qy, P.y, __fmul_rn(qx, P.x)));
        float d2  = __fsub_rn(__fadd_rn(qq, P.w), __fmul_rn(2.0f, dot));
        if (d2 < R2_) {
            atomicOr(&bm[o >> 5], 1u << (o & 31));
        }
    }
    __builtin_amdgcn_wave_barrier();

    // selection: lane owns dwords 8*lane .. 8*lane+7 (index-contiguous)
    uint4 a = *(const uint4*)&bm[lane * 8];
    uint4 c = *(const uint4*)&bm[lane * 8 + 4];
    unsigned int wds[8] = {a.x, a.y, a.z, a.w, c.x, c.y, c.z, c.w};
    int tl = 0;
    #pragma unroll
    for (int j = 0; j < 8; ++j) tl += __popc(wds[j]);
    int pre = tl;
    #pragma unroll
    for (int o = 1; o < 64; o <<= 1) { int u = __shfl_up(pre, o); if (lane >= o) pre += u; }
    int cnt = __shfl(pre, 63);
    int r = pre - tl;                       // global rank of this lane's first set bit
    int basei = lane << 8;                  // lane*8 dwords * 32 bits
    __builtin_amdgcn_wave_barrier();        // all bitmap loads done before reuse as sel[]
    int* sel = (int*)bm;                    // first 32 dwords reused as sel[32]
    #pragma unroll
    for (int wd = 0; wd < 8; ++wd) {
        if (r >= S_) break;
        unsigned int bits = wds[wd];
        while (bits && r < S_) {
            int bpos = __builtin_ctz(bits);
            bits &= bits - 1;
            int gidx = basei + (wd << 5) + bpos;
            if (r == 0) bcAll[w] = gidx;
            sel[r] = gidx;
            ++r;
        }
    }
    __builtin_amdgcn_wave_barrier();
    if (lane < S_ && lane >= cnt) sel[lane] = bcAll[w];   // pad with rank-0 index
    __builtin_amdgcn_wave_barrier();

    // gather + write: lane = (s, half); output stores nontemporal (keep ft in L2)
    int s    = lane & 31;
    int half = lane >> 5;
    int p    = sel[s];
    const float* fp = ft + (((size_t)b * N_ + p) << 6) + half * 32;
    float4 v[8];
    #pragma unroll
    for (int j = 0; j < 8; ++j) v[j] = *(const float4*)(fp + j * 4);

    const size_t cst = (size_t)M_ * S_;     // stride between channel planes
    size_t ob = (((size_t)b * 67 + 3 + half * 32) * M_ + m) * S_ + s;
    #pragma unroll
    for (int j = 0; j < 8; ++j) {
        __builtin_nontemporal_store(v[j].x, &out[ob + (4 * j + 0) * cst]);
        __builtin_nontemporal_store(v[j].y, &out[ob + (4 * j + 1) * cst]);
        __builtin_nontemporal_store(v[j].z, &out[ob + (4 * j + 2) * cst]);
        __builtin_nontemporal_store(v[j].w, &out[ob + (4 * j + 3) * cst]);
    }
    if (half == 0) {
        float4 P = xyz4[(size_t)b * N_ + p];
        size_t xb = (((size_t)b * 67 + 0) * M_ + m) * S_ + s;
        __builtin_nontemporal_store(P.x - qx, &out[xb + 0 * cst]);
        __builtin_nontemporal_store(P.y - qy, &out[xb + 1 * cst]);
        __builtin_nontemporal_store(P.z - qz, &out[xb + 2 * cst]);
    }
}

extern "C" void kernel_launch(void* const* d_in, const int* in_sizes, int n_in,
                              void* d_out, int out_size, void* d_ws, size_t ws_size,
                              hipStream_t stream) {
    const float* xyz    = (const float*)d_in[0];   // (B, N, 3)
    const float* newxyz = (const float*)d_in[1];   // (B, M, 3)
    const float* feat   = (const float*)d_in[2];   // (B, C, N)
    float* out = (float*)d_out;                    // (B, 67, M, S)

    char* ws = (char*)d_ws;
    float4* xyz4  = (float4*)(ws + OFF_XYZ4);
    float*  ft    = (float*)(ws + OFF_FT);
    int*    startc= (int*)(ws + OFF_START);
    int*    curc  = (int*)(ws + OFF_CUR);
    float4* spts  = (float4*)(ws + OFF_SPTS);
    int*    ssid  = (int*)(ws + OFF_SSID);

    hipMemsetAsync(curc, 0, (size_t)B_ * CSTRIDE * sizeof(int), stream);
    pack_hist_transpose<<<256 + B_ * (N_ / 64), 256, 0, stream>>>(xyz, xyz4, curc, feat, ft);
    scan_cells    <<<B_, 1024, 0, stream>>>(curc, startc);
    scatter_pts   <<<(B_ * N_) / 256, 256, 0, stream>>>(xyz4, curc, spts, ssid);
    bq_group      <<<(B_ * M_) / 4, 256, 0, stream>>>(spts, ssid, startc, newxyz,
                                                      xyz4, ft, out);
}